// Round 3
// baseline (215.715 us; speedup 1.0000x reference)
//
#include <hip/hip_runtime.h>
#include <hip/hip_bf16.h>

#define NP 48   // packed weights per subnet: w0[5] b0[5] w1[25] b1[5] w2[5] b2 ss rs
constexpr int IN_SZ = 128, OUT_SZ = 128, BATCH = 2048, NSUB = IN_SZ * OUT_SZ;
constexpr int DET_WORDS = 16384;

__device__ __forceinline__ float bcvt(unsigned short u) {
  return __uint_as_float(((unsigned)u) << 16);
}
__device__ __forceinline__ float bf_lo(unsigned u) { return __uint_as_float(u << 16); }
__device__ __forceinline__ float bf_hi(unsigned u) { return __uint_as_float(u & 0xffff0000u); }

__device__ __forceinline__ float silu_f(float z) {
  float t = __builtin_amdgcn_exp2f(z * -1.44269504088896f);   // exp(-z)
  return z * __builtin_amdgcn_rcpf(1.0f + t);
}

__device__ __forceinline__ float eval_subnet(const float* __restrict__ w, float xv) {
  float h1[5], h2[5];
#pragma unroll
  for (int j = 0; j < 5; ++j) h1[j] = silu_f(fmaf(w[j], xv, w[5 + j]));
#pragma unroll
  for (int j = 0; j < 5; ++j) {
    float z = w[35 + j];
#pragma unroll
    for (int k = 0; k < 5; ++k) z = fmaf(w[10 + j * 5 + k], h1[k], z);
    h2[j] = silu_f(z);
  }
  float y = w[45];
#pragma unroll
  for (int k = 0; k < 5; ++k) y = fmaf(w[40 + k], h2[k], y);
  return fmaf(y, w[46], xv * w[47]);   // y*ss + x*rs
}

// ---- dtype detection: 1 = bf16 inputs, 0 = f32 inputs --------------------
// bf16 data: low ushort of each 32b word is a Gaussian bf16 -> exponent field
// (bits [14:7]) in [100,150] essentially always. f32 data: those bits are
// uniform mantissa bits -> ~20% hit. Deterministic across calls (same data).
__global__ __launch_bounds__(256) void detect_dtype(const unsigned* __restrict__ w1w,
                                                    int* __restrict__ flag) {
  __shared__ int cnt;
  if (threadIdx.x == 0) cnt = 0;
  __syncthreads();
  int local = 0;
  for (int i = threadIdx.x; i < DET_WORDS; i += 256) {
    unsigned e = (w1w[i] >> 7) & 0xffu;
    if (e >= 100u && e <= 150u) local++;
  }
  atomicAdd(&cnt, local);
  __syncthreads();
  if (threadIdx.x == 0) *flag = (2 * cnt > DET_WORDS) ? 1 : 0;
}

__device__ __forceinline__ float ldw(const void* p, size_t idx, int bf) {
  return bf ? bcvt(((const unsigned short*)p)[idx]) : ((const float*)p)[idx];
}

// blocks [0,64): pack weights -> wp[o][i][48] f32 (block-uniform reads in main)
// blocks [64,320): convert/copy x -> xp f32 (4 elems/thread)
__global__ __launch_bounds__(256) void pack_all(
    const void* __restrict__ xr,
    const void* __restrict__ w0, const void* __restrict__ b0,
    const void* __restrict__ w1, const void* __restrict__ b1,
    const void* __restrict__ w2, const void* __restrict__ b2,
    const void* __restrict__ ss, const void* __restrict__ rs,
    const int* __restrict__ flagp, float* __restrict__ wp, float* __restrict__ xp) {
  const int bf = *flagp;
  const int gid = blockIdx.x;
  if (gid < 64) {
    int n = gid * 256 + threadIdx.x;      // subnet id: n = i*128 + o
    int o = n & (OUT_SZ - 1);
    int i = n >> 7;
    float* d = wp + ((size_t)o * IN_SZ + i) * NP;
#pragma unroll
    for (int j = 0; j < 5; ++j) {
      d[j]      = ldw(w0, (size_t)n * 5 + j, bf);
      d[5 + j]  = ldw(b0, (size_t)n * 5 + j, bf);
      d[35 + j] = ldw(b1, (size_t)n * 5 + j, bf);
      d[40 + j] = ldw(w2, (size_t)n * 5 + j, bf);
    }
#pragma unroll
    for (int k = 0; k < 25; ++k) d[10 + k] = ldw(w1, (size_t)n * 25 + k, bf);
    d[45] = ldw(b2, n, bf);
    d[46] = ldw(ss, n, bf);
    d[47] = ldw(rs, n, bf);
  } else {
    int t = (gid - 64) * 256 + threadIdx.x;   // 0..65535, 4 elements each
    size_t base = (size_t)t * 4;
    float v0, v1, v2, v3;
    if (bf) {
      uint2 u = *(const uint2*)((const unsigned short*)xr + base);
      v0 = bf_lo(u.x); v1 = bf_hi(u.x); v2 = bf_lo(u.y); v3 = bf_hi(u.y);
    } else {
      float4 f = *(const float4*)((const float*)xr + base);
      v0 = f.x; v1 = f.y; v2 = f.z; v3 = f.w;
    }
    xp[base] = v0; xp[base + 1] = v1; xp[base + 2] = v2; xp[base + 3] = v3;
  }
}

// Grid: 128 o-blocks x 8 b-chunks; thread = one batch row.
// out[b][o] = sum_i eval(subnet n=i*128+o, x[b,i]);  OUTPUT IS FLOAT32.
__global__ __launch_bounds__(256) void mlp_main(
    const float* __restrict__ xp, const float* __restrict__ wp,
    float* __restrict__ out) {
  int tid = threadIdx.x;
  int o = blockIdx.x & (OUT_SZ - 1);
  int b = (blockIdx.x >> 7) * 256 + tid;
  const float* __restrict__ wbase = wp + (size_t)o * (IN_SZ * NP);
  const float4* __restrict__ xrow = (const float4*)(xp + (size_t)b * IN_SZ);

  float acc = 0.0f;
#pragma unroll 1
  for (int c = 0; c < 32; ++c) {
    float4 xv = xrow[c];
    const float* wc = wbase + (size_t)(c * 4) * NP;
    acc += eval_subnet(wc + 0 * NP, xv.x);
    acc += eval_subnet(wc + 1 * NP, xv.y);
    acc += eval_subnet(wc + 2 * NP, xv.z);
    acc += eval_subnet(wc + 3 * NP, xv.w);
  }
  out[(size_t)b * OUT_SZ + o] = acc;
}

// ---- fallback (workspace too small): read raw f32 directly ----------------
__global__ __launch_bounds__(256) void mlp_raw_f32(
    const float* __restrict__ x,
    const float* __restrict__ w0, const float* __restrict__ b0,
    const float* __restrict__ w1, const float* __restrict__ b1,
    const float* __restrict__ w2, const float* __restrict__ b2,
    const float* __restrict__ ss, const float* __restrict__ rs,
    float* __restrict__ out) {
  int tid = threadIdx.x;
  int o = blockIdx.x & (OUT_SZ - 1);
  int b = (blockIdx.x >> 7) * 256 + tid;
  const float4* __restrict__ xrow = (const float4*)(x + (size_t)b * IN_SZ);
  float acc = 0.0f;
#pragma unroll 1
  for (int c = 0; c < 32; ++c) {
    float4 xv = xrow[c];
    float xs[4] = {xv.x, xv.y, xv.z, xv.w};
#pragma unroll
    for (int r = 0; r < 4; ++r) {
      int n = (c * 4 + r) * OUT_SZ + o;
      float w[NP];
#pragma unroll
      for (int j = 0; j < 5; ++j) {
        w[j]      = w0[(size_t)n * 5 + j];
        w[5 + j]  = b0[(size_t)n * 5 + j];
        w[35 + j] = b1[(size_t)n * 5 + j];
        w[40 + j] = w2[(size_t)n * 5 + j];
      }
#pragma unroll
      for (int k = 0; k < 25; ++k) w[10 + k] = w1[(size_t)n * 25 + k];
      w[45] = b2[n]; w[46] = ss[n]; w[47] = rs[n];
      acc += eval_subnet(w, xs[r]);
    }
  }
  out[(size_t)b * OUT_SZ + o] = acc;
}

extern "C" void kernel_launch(void* const* d_in, const int* in_sizes, int n_in,
                              void* d_out, int out_size, void* d_ws, size_t ws_size,
                              hipStream_t stream) {
  const size_t WP_BYTES = (size_t)NSUB * NP * sizeof(float);        // 3,145,728
  const size_t XP_BYTES = (size_t)BATCH * IN_SZ * sizeof(float);    // 1,048,576
  const size_t NEED = WP_BYTES + XP_BYTES + sizeof(int);

  if (ws_size >= NEED) {
    float* wp = (float*)d_ws;
    float* xp = (float*)((char*)d_ws + WP_BYTES);
    int* flag = (int*)((char*)d_ws + WP_BYTES + XP_BYTES);
    detect_dtype<<<dim3(1), dim3(256), 0, stream>>>((const unsigned*)d_in[3], flag);
    pack_all<<<dim3(64 + 256), dim3(256), 0, stream>>>(
        d_in[0], d_in[1], d_in[2], d_in[3], d_in[4], d_in[5], d_in[6], d_in[7],
        d_in[8], flag, wp, xp);
    mlp_main<<<dim3(OUT_SZ * (BATCH / 256)), dim3(256), 0, stream>>>(
        xp, wp, (float*)d_out);
  } else {
    mlp_raw_f32<<<dim3(OUT_SZ * (BATCH / 256)), dim3(256), 0, stream>>>(
        (const float*)d_in[0], (const float*)d_in[1], (const float*)d_in[2],
        (const float*)d_in[3], (const float*)d_in[4], (const float*)d_in[5],
        (const float*)d_in[6], (const float*)d_in[7], (const float*)d_in[8],
        (float*)d_out);
  }
}

// Round 4
// 201.365 us; speedup vs baseline: 1.0713x; 1.0713x over previous
//
#include <hip/hip_runtime.h>

// MLPKANlayer: 16384 tiny 1->5->5->1 SiLU MLPs (n = i*128 + o), batch 2048.
// out[b][o] = sum_i [ y(n,x[b,i])*ss[n] + x[b,i]*rs[n] ],  n = i*128+o.
// All inputs/outputs are float32 (established empirically in R1-R3).
//
// Design: one kernel. Block = 512 threads (8 waves) = (o, b-chunk); waves 0-3
// evaluate i in [0,64), waves 4-7 evaluate i in [64,128) -> 8192 waves total
// = 100% occupancy. Weight indices depend only on (o, loop counter, wave-half
// via readfirstlane) -> wave-uniform -> compiler emits s_load (SGPR broadcast,
// zero per-lane VMEM for weights). Halves combined via LDS pair-reduce.

constexpr int IN_SZ = 128, OUT_SZ = 128, BATCH = 2048;

__device__ __forceinline__ float silu_f(float z) {
  float t = __builtin_amdgcn_exp2f(z * -1.44269504088896f);   // exp(-z)
  return z * __builtin_amdgcn_rcpf(1.0f + t);
}

__device__ __forceinline__ float eval_subnet(
    int n,
    const float* __restrict__ w0, const float* __restrict__ b0,
    const float* __restrict__ w1, const float* __restrict__ b1,
    const float* __restrict__ w2, const float* __restrict__ b2,
    const float* __restrict__ ss, const float* __restrict__ rs,
    float xv) {
  float h1[5], h2[5];
#pragma unroll
  for (int j = 0; j < 5; ++j)
    h1[j] = silu_f(fmaf(w0[n * 5 + j], xv, b0[n * 5 + j]));
#pragma unroll
  for (int j = 0; j < 5; ++j) {
    float z = b1[n * 5 + j];
#pragma unroll
    for (int k = 0; k < 5; ++k) z = fmaf(w1[n * 25 + j * 5 + k], h1[k], z);
    h2[j] = silu_f(z);
  }
  float y = b2[n];
#pragma unroll
  for (int k = 0; k < 5; ++k) y = fmaf(w2[n * 5 + k], h2[k], y);
  return fmaf(y, ss[n], xv * rs[n]);
}

__global__ __launch_bounds__(512) void mlp_fused(
    const float* __restrict__ x,
    const float* __restrict__ w0, const float* __restrict__ b0,
    const float* __restrict__ w1, const float* __restrict__ b1,
    const float* __restrict__ w2, const float* __restrict__ b2,
    const float* __restrict__ ss, const float* __restrict__ rs,
    float* __restrict__ out) {
  __shared__ float red[256];

  const int tid  = threadIdx.x;
  // wave id as a compiler-provable scalar -> keeps weight addresses uniform
  const int wave = __builtin_amdgcn_readfirstlane(tid) >> 6;  // 0..7
  const int lane = tid & 63;
  const int half = wave >> 2;   // 0: i in [0,64), 1: i in [64,128)
  const int sub  = wave & 3;    // which 64-row slice of the 256-row b-chunk

  const int o     = blockIdx.x & (OUT_SZ - 1);
  const int chunk = blockIdx.x >> 7;            // 0..7
  const int b     = chunk * 256 + sub * 64 + lane;
  const int i0    = half * 64;

  const float4* __restrict__ xrow =
      (const float4*)(x + (size_t)b * IN_SZ + i0);

  float acc = 0.0f;
#pragma unroll 1
  for (int c = 0; c < 16; ++c) {
    float4 xv = xrow[c];
    int n0 = (i0 + c * 4) * OUT_SZ + o;   // n = i*128 + o, i = i0 + c*4 + r
    acc += eval_subnet(n0 + 0 * OUT_SZ, w0, b0, w1, b1, w2, b2, ss, rs, xv.x);
    acc += eval_subnet(n0 + 1 * OUT_SZ, w0, b0, w1, b1, w2, b2, ss, rs, xv.y);
    acc += eval_subnet(n0 + 2 * OUT_SZ, w0, b0, w1, b1, w2, b2, ss, rs, xv.z);
    acc += eval_subnet(n0 + 3 * OUT_SZ, w0, b0, w1, b1, w2, b2, ss, rs, xv.w);
  }

  // combine the two i-halves: partner threads share (sub, lane) -> same b
  if (half) red[sub * 64 + lane] = acc;
  __syncthreads();
  if (!half) out[(size_t)b * OUT_SZ + o] = acc + red[sub * 64 + lane];
}

extern "C" void kernel_launch(void* const* d_in, const int* in_sizes, int n_in,
                              void* d_out, int out_size, void* d_ws, size_t ws_size,
                              hipStream_t stream) {
  const float* x  = (const float*)d_in[0];
  const float* w0 = (const float*)d_in[1];
  const float* b0 = (const float*)d_in[2];
  const float* w1 = (const float*)d_in[3];
  const float* b1 = (const float*)d_in[4];
  const float* w2 = (const float*)d_in[5];
  const float* b2 = (const float*)d_in[6];
  const float* ss = (const float*)d_in[7];
  const float* rs = (const float*)d_in[8];

  mlp_fused<<<dim3(OUT_SZ * (BATCH / 256)), dim3(512), 0, stream>>>(
      x, w0, b0, w1, b1, w2, b2, ss, rs, (float*)d_out);
}

// Round 5
// 160.696 us; speedup vs baseline: 1.3424x; 1.2531x over previous
//
#include <hip/hip_runtime.h>

// MLPKANlayer: 16384 tiny 1->5->5->1 SiLU MLPs (n = i*128 + o), batch 2048.
// out[b][o] = sum_i [ y(n, x[b,i])*ss[n] + x[b,i]*rs[n] ],  n = i*128+o.
// f32 in / f32 out (established R1-R3).
//
// R5: pack kernel (weights -> wp[o][i][48], contiguous block-uniform s_loads)
//     + single main kernel: 1024 blocks x 512 threads = 8192 waves (100% cap).
//     Thread = 2 batch rows (b, b+1024) x 32 i-values -> float2 math the
//     compiler can fuse to v_pk_fma_f32; weights/biases amortized over the
//     pair. i split into quarters across wave-pairs; LDS tree-combine.

#define NP 48   // w0[5] b0[5] w1[25] b1[5] w2[5] b2 ss rs
constexpr int IN_SZ = 128, OUT_SZ = 128, BATCH = 2048, NSUB = IN_SZ * OUT_SZ;

struct f2 { float x, y; };

__device__ __forceinline__ f2 silu2(f2 z) {
  constexpr float NL2E = -1.44269504088896f;
  float tx = __builtin_amdgcn_exp2f(z.x * NL2E);   // exp(-z)
  float ty = __builtin_amdgcn_exp2f(z.y * NL2E);
  float rx = __builtin_amdgcn_rcpf(1.0f + tx);
  float ry = __builtin_amdgcn_rcpf(1.0f + ty);
  return { z.x * rx, z.y * ry };
}

__device__ __forceinline__ void eval_pair(const float* __restrict__ w, f2 xv,
                                          f2& acc) {
  f2 h1[5], h2[5];
#pragma unroll
  for (int j = 0; j < 5; ++j) {
    f2 z { fmaf(w[j], xv.x, w[5 + j]), fmaf(w[j], xv.y, w[5 + j]) };
    h1[j] = silu2(z);
  }
#pragma unroll
  for (int j = 0; j < 5; ++j) {
    f2 z { w[35 + j], w[35 + j] };
#pragma unroll
    for (int k = 0; k < 5; ++k) {
      float ww = w[10 + j * 5 + k];
      z.x = fmaf(ww, h1[k].x, z.x);
      z.y = fmaf(ww, h1[k].y, z.y);
    }
    h2[j] = silu2(z);
  }
  f2 y { w[45], w[45] };
#pragma unroll
  for (int k = 0; k < 5; ++k) {
    float ww = w[40 + k];
    y.x = fmaf(ww, h2[k].x, y.x);
    y.y = fmaf(ww, h2[k].y, y.y);
  }
  acc.x = fmaf(y.x, w[46], fmaf(xv.x, w[47], acc.x));
  acc.y = fmaf(y.y, w[46], fmaf(xv.y, w[47], acc.y));
}

// ---- pack weights: raw arrays -> wp[o][i][48] ------------------------------
__global__ __launch_bounds__(256) void pack_w(
    const float* __restrict__ w0, const float* __restrict__ b0,
    const float* __restrict__ w1, const float* __restrict__ b1,
    const float* __restrict__ w2, const float* __restrict__ b2,
    const float* __restrict__ ss, const float* __restrict__ rs,
    float* __restrict__ wp) {
  int n = blockIdx.x * 256 + threadIdx.x;   // subnet id: n = i*128 + o
  int o = n & (OUT_SZ - 1);
  int i = n >> 7;
  float* d = wp + ((size_t)o * IN_SZ + i) * NP;
#pragma unroll
  for (int j = 0; j < 5; ++j) {
    d[j]      = w0[(size_t)n * 5 + j];
    d[5 + j]  = b0[(size_t)n * 5 + j];
    d[35 + j] = b1[(size_t)n * 5 + j];
    d[40 + j] = w2[(size_t)n * 5 + j];
  }
#pragma unroll
  for (int k = 0; k < 25; ++k) d[10 + k] = w1[(size_t)n * 25 + k];
  d[45] = b2[n]; d[46] = ss[n]; d[47] = rs[n];
}

// ---- main: block = (o, 128-pair chunk); wave-pair q handles i-quarter ------
__global__ __launch_bounds__(512) void mlp_main2(
    const float* __restrict__ x, const float* __restrict__ wp,
    float* __restrict__ out) {
  __shared__ f2 red[3][128];

  const int tid  = threadIdx.x;
  const int wv   = __builtin_amdgcn_readfirstlane(tid >> 6);  // 0..7, uniform
  const int lane = tid & 63;
  const int q    = wv >> 1;          // i-quarter: i in [32q, 32q+32)
  const int p    = wv & 1;           // pair-group within chunk

  const int o     = blockIdx.x & (OUT_SZ - 1);
  const int chunk = blockIdx.x >> 7;          // 0..7
  const int pl    = p * 64 + lane;            // 0..127
  const int b0    = chunk * 128 + pl;         // row A
  const int b1    = b0 + 1024;                // row B
  const int i0    = q * 32;

  const float* __restrict__ wbase = wp + ((size_t)o * IN_SZ + i0) * NP;
  const float4* __restrict__ xr0 = (const float4*)(x + (size_t)b0 * IN_SZ + i0);
  const float4* __restrict__ xr1 = (const float4*)(x + (size_t)b1 * IN_SZ + i0);

  f2 acc { 0.0f, 0.0f };
#pragma unroll 1
  for (int c = 0; c < 8; ++c) {
    float4 xa = xr0[c];
    float4 xb = xr1[c];
    const float* wc = wbase + (size_t)(c * 4) * NP;
    eval_pair(wc + 0 * NP, { xa.x, xb.x }, acc);
    eval_pair(wc + 1 * NP, { xa.y, xb.y }, acc);
    eval_pair(wc + 2 * NP, { xa.z, xb.z }, acc);
    eval_pair(wc + 3 * NP, { xa.w, xb.w }, acc);
  }

  if (q) red[q - 1][pl] = acc;
  __syncthreads();
  if (!q) {
    f2 r1 = red[0][pl], r2 = red[1][pl], r3 = red[2][pl];
    out[(size_t)b0 * OUT_SZ + o] = acc.x + r1.x + r2.x + r3.x;
    out[(size_t)b1 * OUT_SZ + o] = acc.y + r1.y + r2.y + r3.y;
  }
}

// ---- fallback (ws too small): R4's raw-array kernel ------------------------
__device__ __forceinline__ float silu_f(float z) {
  float t = __builtin_amdgcn_exp2f(z * -1.44269504088896f);
  return z * __builtin_amdgcn_rcpf(1.0f + t);
}

__global__ __launch_bounds__(512) void mlp_raw(
    const float* __restrict__ x,
    const float* __restrict__ w0, const float* __restrict__ b0,
    const float* __restrict__ w1, const float* __restrict__ b1,
    const float* __restrict__ w2, const float* __restrict__ b2,
    const float* __restrict__ ss, const float* __restrict__ rs,
    float* __restrict__ out) {
  __shared__ float red[256];
  const int tid  = threadIdx.x;
  const int wave = __builtin_amdgcn_readfirstlane(tid) >> 6;
  const int lane = tid & 63;
  const int half = wave >> 2;
  const int sub  = wave & 3;
  const int o     = blockIdx.x & (OUT_SZ - 1);
  const int chunk = blockIdx.x >> 7;
  const int b     = chunk * 256 + sub * 64 + lane;
  const int i0    = half * 64;
  const float4* __restrict__ xrow = (const float4*)(x + (size_t)b * IN_SZ + i0);
  float acc = 0.0f;
#pragma unroll 1
  for (int c = 0; c < 16; ++c) {
    float4 xv = xrow[c];
    float xs[4] = { xv.x, xv.y, xv.z, xv.w };
#pragma unroll
    for (int r = 0; r < 4; ++r) {
      int n = (i0 + c * 4 + r) * OUT_SZ + o;
      float h1[5], h2[5];
#pragma unroll
      for (int j = 0; j < 5; ++j)
        h1[j] = silu_f(fmaf(w0[n * 5 + j], xs[r], b0[n * 5 + j]));
#pragma unroll
      for (int j = 0; j < 5; ++j) {
        float z = b1[n * 5 + j];
#pragma unroll
        for (int k = 0; k < 5; ++k) z = fmaf(w1[n * 25 + j * 5 + k], h1[k], z);
        h2[j] = silu_f(z);
      }
      float y = b2[n];
#pragma unroll
      for (int k = 0; k < 5; ++k) y = fmaf(w2[n * 5 + k], h2[k], y);
      acc += fmaf(y, ss[n], xs[r] * rs[n]);
    }
  }
  if (half) red[sub * 64 + lane] = acc;
  __syncthreads();
  if (!half) out[(size_t)b * OUT_SZ + o] = acc + red[sub * 64 + lane];
}

extern "C" void kernel_launch(void* const* d_in, const int* in_sizes, int n_in,
                              void* d_out, int out_size, void* d_ws, size_t ws_size,
                              hipStream_t stream) {
  const float* x  = (const float*)d_in[0];
  const float* w0 = (const float*)d_in[1];
  const float* b0 = (const float*)d_in[2];
  const float* w1 = (const float*)d_in[3];
  const float* b1 = (const float*)d_in[4];
  const float* w2 = (const float*)d_in[5];
  const float* b2 = (const float*)d_in[6];
  const float* ss = (const float*)d_in[7];
  const float* rs = (const float*)d_in[8];
  const size_t WP_BYTES = (size_t)NSUB * NP * sizeof(float);   // 3 MiB

  if (ws_size >= WP_BYTES) {
    float* wp = (float*)d_ws;
    pack_w<<<dim3(NSUB / 256), dim3(256), 0, stream>>>(
        w0, b0, w1, b1, w2, b2, ss, rs, wp);
    mlp_main2<<<dim3(OUT_SZ * 8), dim3(512), 0, stream>>>(
        x, wp, (float*)d_out);
  } else {
    mlp_raw<<<dim3(OUT_SZ * (BATCH / 256)), dim3(512), 0, stream>>>(
        x, w0, b0, w1, b1, w2, b2, ss, rs, (float*)d_out);
  }
}